// Round 7
// baseline (253.121 us; speedup 1.0000x reference)
//
#include <hip/hip_runtime.h>
#include <stdint.h>

#define BB 4
#define TT 2048
#define DD 1024

typedef unsigned short u16;
typedef unsigned int u32;
typedef u16 u16x4 __attribute__((ext_vector_type(4)));
typedef u16 u16x8 __attribute__((ext_vector_type(8)));
typedef float f32x4 __attribute__((ext_vector_type(4)));
typedef short s16x8 __attribute__((ext_vector_type(8)));

__device__ __forceinline__ u16 f2bf(float f) {
  u32 u = __float_as_uint(f);
  return (u16)((u + 0x7fffu + ((u >> 16) & 1u)) >> 16);
}
__device__ __forceinline__ float bf2f(u16 h) {
  return __uint_as_float((u32)h << 16);
}

__device__ __forceinline__ void gload_lds16(const void* g, void* l) {
  __builtin_amdgcn_global_load_lds(
      (const __attribute__((address_space(1))) u32*)g,
      (__attribute__((address_space(3))) u32*)l, 16, 0, 0);
}

// XCD-aware block swizzle (bijection; gridM%4==0, gridN%2==0 required).
__device__ __forceinline__ void swizzle_tiles(int& tileM, int& tileN) {
  const int gN = gridDim.x, gM = gridDim.y;
  const int L = blockIdx.y * gN + blockIdx.x;
  const int xcd = L & 7, j = L >> 3;
  const int Mq = gM >> 2, Nq = gN >> 1;
  tileM = (((xcd >> 1) * Mq) + j / Nq) << 7;
  tileN = (((xcd & 1) * Nq) + j % Nq) << 7;
}

// ------------------------------------------------- merged prep kernel
__global__ __launch_bounds__(256) void prep_kernel(
    const float* __restrict__ x, const float* __restrict__ wq,
    const float* __restrict__ wk, const float* __restrict__ wv,
    const float* __restrict__ bq, const float* __restrict__ bk,
    const float* __restrict__ bv, u16* __restrict__ xbf,
    u16* __restrict__ wcat, float* __restrict__ bcat) {
  const int bid = blockIdx.x;
  const int tid = threadIdx.x;
  if (bid < 4096) {
    const size_t i = (size_t)bid * 256 + tid;
    const f32x4* p = (const f32x4*)x;
    f32x4 a = p[2 * i];
    f32x4 b = p[2 * i + 1];
    u16x8 o;
    o[0] = f2bf(a[0]); o[1] = f2bf(a[1]); o[2] = f2bf(a[2]); o[3] = f2bf(a[3]);
    o[4] = f2bf(b[0]); o[5] = f2bf(b[1]); o[6] = f2bf(b[2]); o[7] = f2bf(b[3]);
    *(u16x8*)(xbf + 8 * i) = o;
  } else if (bid < 5632) {
    const int i = (bid - 4096) * 256 + tid;
    const int n1 = DD * DD / 8;
    const float* src = i < n1 ? wq : (i < 2 * n1 ? wk : wv);
    const int ii = i < n1 ? i : (i < 2 * n1 ? i - n1 : i - 2 * n1);
    const f32x4* p = (const f32x4*)src;
    f32x4 a = p[2 * (size_t)ii];
    f32x4 b = p[2 * (size_t)ii + 1];
    u16x8 o;
    o[0] = f2bf(a[0]); o[1] = f2bf(a[1]); o[2] = f2bf(a[2]); o[3] = f2bf(a[3]);
    o[4] = f2bf(b[0]); o[5] = f2bf(b[1]); o[6] = f2bf(b[2]); o[7] = f2bf(b[3]);
    *(u16x8*)(wcat + 8 * (size_t)i) = o;
  } else {
    const int i = (bid - 5632) * 256 + tid;
    if (i < 3 * DD) {
      float v = i < DD ? bq[i] : (i < 2 * DD ? bk[i - DD] : bv[i - 2 * DD]);
      bcat[i] = v;
    }
  }
}

// -------------------------------------------------- register-dieted BK=64 loop
// Same data movement as round 3/6 (measured 845 TF, 0 conflicts), but:
//  - A and B share ONE set of 4 u32 byte-offsets (lda==ldb for all callers),
//    uniform SGPR bases -> saddr-form global_load_lds (1 VGPR per addr).
//  - ds_read: 1 base VGPR per operand + immediate offsets; second K-half
//    via address^64 (chunk-XOR swizzle, conflict-free).
// Goal: arch VGPR <= 64 so total (incl. 64 acc) <= 128 -> 4 waves/SIMD.
__device__ __forceinline__ void kloop_bt(
    const u16* __restrict__ Ab, const u16* __restrict__ Bb, int ld, int K,
    u16* sA, u16* sB, f32x4 acc[4][4]) {
  const int tid = threadIdx.x;
  const int lane = tid & 63;
  const int wave = tid >> 6;
  const int quad = lane >> 4;
  const int l15 = lane & 15;
  const int wm = (wave >> 1) << 6;
  const int wn = (wave & 1) << 6;

  // shared per-lane staging offsets (bytes), identical for A and B
  u32 goff[4];
#pragma unroll
  for (int j = 0; j < 4; ++j) {
    const int ch = wave * 256 + j * 64 + lane;
    const int r = ch >> 3;
    const int cg = ((ch & 7) ^ (r & 7)) * 8;
    goff[j] = (u32)((r * ld + cg) * 2);
  }
  u16* lA = sA + wave * 2048;
  u16* lB = sB + wave * 2048;

  // fragment-read bases (bytes into LDS), imm offsets i*2048, half2 = ^64
  const int x0 = (quad ^ (l15 & 7)) * 8;
  u16* aRd = sA + (wm + l15) * 64 + x0;
  u16* bRd = sB + (wn + l15) * 64 + x0;

  for (int it = 0; it < K; it += 64) {
#pragma unroll
    for (int j = 0; j < 4; ++j)
      gload_lds16((const char*)Ab + goff[j], lA + j * 512);
#pragma unroll
    for (int j = 0; j < 4; ++j)
      gload_lds16((const char*)Bb + goff[j], lB + j * 512);
#pragma unroll
    for (int j = 0; j < 4; ++j) goff[j] += 128;
    __syncthreads();

    s16x8 af[4], bf[4];
#pragma unroll
    for (int i = 0; i < 4; ++i) af[i] = *(const s16x8*)(aRd + i * 1024);
#pragma unroll
    for (int i = 0; i < 4; ++i) bf[i] = *(const s16x8*)(bRd + i * 1024);
#pragma unroll
    for (int mi = 0; mi < 4; ++mi)
#pragma unroll
      for (int ni = 0; ni < 4; ++ni)
        acc[mi][ni] = __builtin_amdgcn_mfma_f32_16x16x32_bf16(
            af[mi], bf[ni], acc[mi][ni], 0, 0, 0);

    const u16* aRd2 = (const u16*)((uintptr_t)aRd ^ 64);
    const u16* bRd2 = (const u16*)((uintptr_t)bRd ^ 64);
#pragma unroll
    for (int i = 0; i < 4; ++i) af[i] = *(const s16x8*)(aRd2 + i * 1024);
#pragma unroll
    for (int i = 0; i < 4; ++i) bf[i] = *(const s16x8*)(bRd2 + i * 1024);
#pragma unroll
    for (int mi = 0; mi < 4; ++mi)
#pragma unroll
      for (int ni = 0; ni < 4; ++ni)
        acc[mi][ni] = __builtin_amdgcn_mfma_f32_16x16x32_bf16(
            af[mi], bf[ni], acc[mi][ni], 0, 0, 0);
    __syncthreads();
  }
}

// -------------------------------------------------- fused QKV projection
__global__ __launch_bounds__(256, 4) void gemm_qkv(
    const u16* __restrict__ A, const u16* __restrict__ B,
    u16* __restrict__ qk, u16* __restrict__ vt, const float* __restrict__ bias) {
  __shared__ u16 sA[128 * 64];
  __shared__ u16 sB[128 * 64];
  const int lane = threadIdx.x & 63;
  const int wave = threadIdx.x >> 6;
  const int quad = lane >> 4;
  const int l15 = lane & 15;
  const int wm = (wave >> 1) << 6;
  const int wn = (wave & 1) << 6;
  int tileM, tileN;
  swizzle_tiles(tileM, tileN);

  f32x4 acc[4][4] = {};
  kloop_bt(A + (size_t)tileM * DD, B + (size_t)tileN * DD, DD, DD, sA, sB,
           acc);

  const int rowB = tileM + wm + quad * 4;
  const int colB = tileN + wn + l15;
  if (tileN < 2048) {
    const float scale = (tileN < 1024) ? 0.03125f : 1.0f;  // 1/sqrt(1024)
#pragma unroll
    for (int mi = 0; mi < 4; ++mi)
#pragma unroll
      for (int r = 0; r < 4; ++r) {
        u16* crow = qk + (size_t)(rowB + mi * 16 + r) * 2048 + colB;
#pragma unroll
        for (int ni = 0; ni < 4; ++ni)
          crow[ni * 16] = f2bf((acc[mi][ni][r] + bias[colB + ni * 16]) * scale);
      }
  } else {
    const int b = tileM >> 11;
    const int tBase = (rowB & 2047);
    u16* vb = vt + (size_t)b * DD * TT;
#pragma unroll
    for (int mi = 0; mi < 4; ++mi)
#pragma unroll
      for (int ni = 0; ni < 4; ++ni) {
        const int e = colB + ni * 16 - 2048;
        const float bs = bias[colB + ni * 16];
        u16x4 o;
#pragma unroll
        for (int r = 0; r < 4; ++r) o[r] = f2bf(acc[mi][ni][r] + bs);
        *(u16x4*)(vb + (size_t)e * TT + tBase + mi * 16) = o;
      }
  }
}

// -------------------------------------------------- S-gemm + exp + partials
// No max-subtraction: scores ~N(0,1) -> exp safe in fp32; ratio identical.
__global__ __launch_bounds__(256, 4) void gemm_s(
    const u16* __restrict__ qk, u16* __restrict__ sbuf,
    float* __restrict__ part) {
  __shared__ u16 sA[128 * 64];
  __shared__ u16 sB[128 * 64];
  const int lane = threadIdx.x & 63;
  const int wave = threadIdx.x >> 6;
  const int quad = lane >> 4;
  const int l15 = lane & 15;
  const int wm = (wave >> 1) << 6;
  const int wn = (wave & 1) << 6;
  int tileM, tileN;
  swizzle_tiles(tileM, tileN);
  const int z = blockIdx.z;

  const u16* A = qk + (size_t)z * TT * 2048 + (size_t)tileM * 2048;
  const u16* B = qk + (size_t)z * TT * 2048 + 1024 + (size_t)tileN * 2048;

  f32x4 acc[4][4] = {};
  kloop_bt(A, B, 2048, 1024, sA, sB, acc);

  const int rowB = tileM + wm + quad * 4;
  const int colB = tileN + wn + l15;
  u16* C = sbuf + (size_t)z * TT * 2048;
  const int nIdx2 = (tileN + wn) >> 6;  // 0..31
  float* prow = part + ((size_t)z * 32 + nIdx2) * TT;
#pragma unroll
  for (int mi = 0; mi < 4; ++mi)
#pragma unroll
    for (int r = 0; r < 4; ++r) {
      const int row = rowB + mi * 16 + r;
      u16* crow = C + (size_t)row * 2048 + colB;
      float s = 0.f;
#pragma unroll
      for (int ni = 0; ni < 4; ++ni) {
        const u16 h = f2bf(__expf(acc[mi][ni][r]));
        crow[ni * 16] = h;
        s += bf2f(h);  // sum ROUNDED values -> exact convex combination
      }
#pragma unroll
      for (int m = 1; m <= 8; m <<= 1) s += __shfl_xor(s, m, 64);
      if (l15 == 0) prow[row] = s;
    }
}

// -------------------------------------------------- PV gemm + normalize
__global__ __launch_bounds__(256, 4) void gemm_pv(
    const u16* __restrict__ sbuf, const u16* __restrict__ vt,
    float* __restrict__ out, const float* __restrict__ part) {
  __shared__ u16 sA[128 * 64];
  __shared__ u16 sB[128 * 64];
  __shared__ float rowInv[128];
  const int tid = threadIdx.x;
  const int lane = tid & 63;
  const int wave = tid >> 6;
  const int quad = lane >> 4;
  const int l15 = lane & 15;
  const int wm = (wave >> 1) << 6;
  const int wn = (wave & 1) << 6;
  int tileM, tileN;
  swizzle_tiles(tileM, tileN);
  const int z = blockIdx.z;

  if (tid < 128) {
    const float* pp = part + (size_t)z * 32 * TT + tileM + tid;
    float s = 0.f;
#pragma unroll
    for (int j = 0; j < 32; ++j) s += pp[j * TT];
    rowInv[tid] = 1.0f / s;
  }
  // visible after the K-loop's barriers; consumed in epilogue

  const u16* A = sbuf + (size_t)z * TT * 2048 + (size_t)tileM * 2048;
  const u16* B = vt + (size_t)z * DD * TT + (size_t)tileN * 2048;

  f32x4 acc[4][4] = {};
  kloop_bt(A, B, 2048, 2048, sA, sB, acc);

  const int rowB = tileM + wm + quad * 4;
  const int colB = tileN + wn + l15;
  float* C = out + (size_t)z * TT * DD;
#pragma unroll
  for (int mi = 0; mi < 4; ++mi)
#pragma unroll
    for (int r = 0; r < 4; ++r) {
      const float inv = rowInv[wm + quad * 4 + mi * 16 + r];
      float* crow = C + (size_t)(rowB + mi * 16 + r) * DD + colB;
#pragma unroll
      for (int ni = 0; ni < 4; ++ni) crow[ni * 16] = acc[mi][ni][r] * inv;
    }
}

// ---------------------------------------------------------------- launcher
extern "C" void kernel_launch(void* const* d_in, const int* in_sizes, int n_in,
                              void* d_out, int out_size, void* d_ws,
                              size_t ws_size, hipStream_t stream) {
  const float* x = (const float*)d_in[0];
  const float* wq = (const float*)d_in[1];
  const float* bq = (const float*)d_in[2];
  const float* wk = (const float*)d_in[3];
  const float* bk = (const float*)d_in[4];
  const float* wv = (const float*)d_in[5];
  const float* bv = (const float*)d_in[6];
  float* out = (float*)d_out;

  const size_t MB = 1024 * 1024;
  // Workspace:
  //  [0,16)  xbf (dead after QKV); part [4][32][2048] fp32 aliases its head
  //          (written by gemm_s AFTER QKV consumed xbf).
  //  [16,22) wcat   [22,+12K) bcat
  //  [23,55) qk [8192][2048] bf16   [55,71) vt [4][1024][2048] bf16
  //  [71,103) sbuf [4][2048][2048] bf16 (unnormalized P)
  if (ws_size < 103 * MB) return;
  char* ws = (char*)d_ws;
  u16* xbf = (u16*)(ws);
  float* part = (float*)(ws);
  u16* wcat = (u16*)(ws + 16 * MB);
  float* bcat = (float*)(ws + 22 * MB);
  u16* qk = (u16*)(ws + 23 * MB);
  u16* vt = (u16*)(ws + 55 * MB);
  u16* sbuf = (u16*)(ws + 71 * MB);

  const dim3 blk(256);

  prep_kernel<<<5644, blk, 0, stream>>>(x, wq, wk, wv, bq, bk, bv, xbf, wcat,
                                        bcat);

  gemm_qkv<<<dim3(3 * DD / 128, BB * TT / 128, 1), blk, 0, stream>>>(
      xbf, wcat, qk, vt, bcat);

  gemm_s<<<dim3(TT / 128, TT / 128, BB), blk, 0, stream>>>(qk, sbuf, part);

  gemm_pv<<<dim3(DD / 128, TT / 128, BB), blk, 0, stream>>>(
      sbuf, vt, out, part);
}

// Round 8
// 236.861 us; speedup vs baseline: 1.0686x; 1.0686x over previous
//
#include <hip/hip_runtime.h>
#include <stdint.h>

#define BB 4
#define TT 2048
#define DD 1024

typedef unsigned short u16;
typedef unsigned int u32;
typedef u16 u16x4 __attribute__((ext_vector_type(4)));
typedef u16 u16x8 __attribute__((ext_vector_type(8)));
typedef float f32x4 __attribute__((ext_vector_type(4)));
typedef short s16x8 __attribute__((ext_vector_type(8)));

__device__ __forceinline__ u16 f2bf(float f) {
  u32 u = __float_as_uint(f);
  return (u16)((u + 0x7fffu + ((u >> 16) & 1u)) >> 16);
}
__device__ __forceinline__ float bf2f(u16 h) {
  return __uint_as_float((u32)h << 16);
}

__device__ __forceinline__ void gload_lds16(const void* g, void* l) {
  __builtin_amdgcn_global_load_lds(
      (const __attribute__((address_space(1))) u32*)g,
      (__attribute__((address_space(3))) u32*)l, 16, 0, 0);
}

// XCD-aware block swizzle (bijection; gridM%4==0, gridN%2==0 required).
__device__ __forceinline__ void swizzle_tiles(int& tileM, int& tileN) {
  const int gN = gridDim.x, gM = gridDim.y;
  const int L = blockIdx.y * gN + blockIdx.x;
  const int xcd = L & 7, j = L >> 3;
  const int Mq = gM >> 2, Nq = gN >> 1;
  tileM = (((xcd >> 1) * Mq) + j / Nq) << 7;
  tileN = (((xcd & 1) * Nq) + j % Nq) << 7;
}

// ------------------------------------------------- merged prep kernel
__global__ __launch_bounds__(256) void prep_kernel(
    const float* __restrict__ x, const float* __restrict__ wq,
    const float* __restrict__ wk, const float* __restrict__ wv,
    const float* __restrict__ bq, const float* __restrict__ bk,
    const float* __restrict__ bv, u16* __restrict__ xbf,
    u16* __restrict__ wcat, float* __restrict__ bcat) {
  const int bid = blockIdx.x;
  const int tid = threadIdx.x;
  if (bid < 4096) {
    const size_t i = (size_t)bid * 256 + tid;
    const f32x4* p = (const f32x4*)x;
    f32x4 a = p[2 * i];
    f32x4 b = p[2 * i + 1];
    u16x8 o;
    o[0] = f2bf(a[0]); o[1] = f2bf(a[1]); o[2] = f2bf(a[2]); o[3] = f2bf(a[3]);
    o[4] = f2bf(b[0]); o[5] = f2bf(b[1]); o[6] = f2bf(b[2]); o[7] = f2bf(b[3]);
    *(u16x8*)(xbf + 8 * i) = o;
  } else if (bid < 5632) {
    const int i = (bid - 4096) * 256 + tid;
    const int n1 = DD * DD / 8;
    const float* src = i < n1 ? wq : (i < 2 * n1 ? wk : wv);
    const int ii = i < n1 ? i : (i < 2 * n1 ? i - n1 : i - 2 * n1);
    const f32x4* p = (const f32x4*)src;
    f32x4 a = p[2 * (size_t)ii];
    f32x4 b = p[2 * (size_t)ii + 1];
    u16x8 o;
    o[0] = f2bf(a[0]); o[1] = f2bf(a[1]); o[2] = f2bf(a[2]); o[3] = f2bf(a[3]);
    o[4] = f2bf(b[0]); o[5] = f2bf(b[1]); o[6] = f2bf(b[2]); o[7] = f2bf(b[3]);
    *(u16x8*)(wcat + 8 * (size_t)i) = o;
  } else {
    const int i = (bid - 5632) * 256 + tid;
    if (i < 3 * DD) {
      float v = i < DD ? bq[i] : (i < 2 * DD ? bk[i - DD] : bv[i - 2 * DD]);
      bcat[i] = v;
    }
  }
}

// -------------------------------------------------- BK=128 K-loop
// Same data movement/occupancy as the measured-best BK=64 loop, but 128 MFMAs
// per barrier pair (4x drain-event amortization). Tile row = 128 elems =
// 16 x 16B chunks; chunk (r,c) STORED at pos (c&8)|((c^r)&7) -> read pattern
// (per kh,quad: pos = ((kh&1)*4+quad)^(l15&7), +bit3 for kh>=2) keeps
// 2 lanes/bank-quad = conflict-free. A,B share one goff set (lda==ldb for
// every caller). LDS: 2 x 32KB -> 2 blocks/CU (unchanged; VGPR-bound anyway).
__device__ __forceinline__ void kloop_bt(
    const u16* __restrict__ Ab, const u16* __restrict__ Bb, int ld, int K,
    u16* sA, u16* sB, f32x4 acc[4][4]) {
  const int tid = threadIdx.x;
  const int lane = tid & 63;
  const int wave = tid >> 6;
  const int quad = lane >> 4;
  const int l15 = lane & 15;
  const int wm = (wave >> 1) << 6;
  const int wn = (wave & 1) << 6;

  // staging: 2048 chunks per matrix; thread stages 8 A + 8 B
  u32 goff[8];
#pragma unroll
  for (int s = 0; s < 8; ++s) {
    const int ch = wave * 512 + s * 64 + lane;
    const int r = ch >> 4, c = ch & 15;
    const int cg = ((c & 8) | ((c ^ (r & 7)) & 7)) * 8;
    goff[s] = (u32)((r * ld + cg) * 2);
  }
  u16* lA = sA + wave * 4096;
  u16* lB = sB + wave * 4096;

  // fragment read offsets (row stride 128 elems)
  const int x0 = (quad ^ (l15 & 7)) * 8;
  int aOff[4], bOff[4];
#pragma unroll
  for (int i = 0; i < 4; ++i) {
    aOff[i] = (wm + i * 16 + l15) * 128 + x0;
    bOff[i] = (wn + i * 16 + l15) * 128 + x0;
  }

  for (int it = 0; it < K; it += 128) {
#pragma unroll
    for (int s = 0; s < 8; ++s)
      gload_lds16((const char*)Ab + goff[s], lA + s * 512);
#pragma unroll
    for (int s = 0; s < 8; ++s)
      gload_lds16((const char*)Bb + goff[s], lB + s * 512);
#pragma unroll
    for (int s = 0; s < 8; ++s) goff[s] += 256;
    __syncthreads();

#pragma unroll
    for (int kh = 0; kh < 4; ++kh) {
      const int add = (kh & 2) << 5;   // +64 elems for kh>=2 (chunk bit3)
      const int xo = (kh & 1) << 5;    // ^32 elems for odd kh
      s16x8 af[4], bf[4];
#pragma unroll
      for (int i = 0; i < 4; ++i)
        af[i] = *(const s16x8*)(sA + ((aOff[i] + add) ^ xo));
#pragma unroll
      for (int i = 0; i < 4; ++i)
        bf[i] = *(const s16x8*)(sB + ((bOff[i] + add) ^ xo));
#pragma unroll
      for (int mi = 0; mi < 4; ++mi)
#pragma unroll
        for (int ni = 0; ni < 4; ++ni)
          acc[mi][ni] = __builtin_amdgcn_mfma_f32_16x16x32_bf16(
              af[mi], bf[ni], acc[mi][ni], 0, 0, 0);
    }
    __syncthreads();
  }
}

// -------------------------------------------------- fused QKV projection
__global__ __launch_bounds__(256, 2) void gemm_qkv(
    const u16* __restrict__ A, const u16* __restrict__ B,
    u16* __restrict__ qk, u16* __restrict__ vt, const float* __restrict__ bias) {
  __shared__ u16 sA[128 * 128];
  __shared__ u16 sB[128 * 128];
  const int lane = threadIdx.x & 63;
  const int wave = threadIdx.x >> 6;
  const int quad = lane >> 4;
  const int l15 = lane & 15;
  const int wm = (wave >> 1) << 6;
  const int wn = (wave & 1) << 6;
  int tileM, tileN;
  swizzle_tiles(tileM, tileN);

  f32x4 acc[4][4] = {};
  kloop_bt(A + (size_t)tileM * DD, B + (size_t)tileN * DD, DD, DD, sA, sB,
           acc);

  const int rowB = tileM + wm + quad * 4;
  const int colB = tileN + wn + l15;
  if (tileN < 2048) {
    const float scale = (tileN < 1024) ? 0.03125f : 1.0f;  // 1/sqrt(1024)
#pragma unroll
    for (int mi = 0; mi < 4; ++mi)
#pragma unroll
      for (int r = 0; r < 4; ++r) {
        u16* crow = qk + (size_t)(rowB + mi * 16 + r) * 2048 + colB;
#pragma unroll
        for (int ni = 0; ni < 4; ++ni)
          crow[ni * 16] = f2bf((acc[mi][ni][r] + bias[colB + ni * 16]) * scale);
      }
  } else {
    const int b = tileM >> 11;
    const int tBase = (rowB & 2047);
    u16* vb = vt + (size_t)b * DD * TT;
#pragma unroll
    for (int mi = 0; mi < 4; ++mi)
#pragma unroll
      for (int ni = 0; ni < 4; ++ni) {
        const int e = colB + ni * 16 - 2048;
        const float bs = bias[colB + ni * 16];
        u16x4 o;
#pragma unroll
        for (int r = 0; r < 4; ++r) o[r] = f2bf(acc[mi][ni][r] + bs);
        *(u16x4*)(vb + (size_t)e * TT + tBase + mi * 16) = o;
      }
  }
}

// -------------------------------------------------- S-gemm + exp + partials
// No max-subtraction: scores ~N(0,1) -> exp safe in fp32; ratio identical.
__global__ __launch_bounds__(256, 2) void gemm_s(
    const u16* __restrict__ qk, u16* __restrict__ sbuf,
    float* __restrict__ part) {
  __shared__ u16 sA[128 * 128];
  __shared__ u16 sB[128 * 128];
  const int lane = threadIdx.x & 63;
  const int wave = threadIdx.x >> 6;
  const int quad = lane >> 4;
  const int l15 = lane & 15;
  const int wm = (wave >> 1) << 6;
  const int wn = (wave & 1) << 6;
  int tileM, tileN;
  swizzle_tiles(tileM, tileN);
  const int z = blockIdx.z;

  const u16* A = qk + (size_t)z * TT * 2048 + (size_t)tileM * 2048;
  const u16* B = qk + (size_t)z * TT * 2048 + 1024 + (size_t)tileN * 2048;

  f32x4 acc[4][4] = {};
  kloop_bt(A, B, 2048, 1024, sA, sB, acc);

  const int rowB = tileM + wm + quad * 4;
  const int colB = tileN + wn + l15;
  u16* C = sbuf + (size_t)z * TT * 2048;
  const int nIdx2 = (tileN + wn) >> 6;  // 0..31
  float* prow = part + ((size_t)z * 32 + nIdx2) * TT;
#pragma unroll
  for (int mi = 0; mi < 4; ++mi)
#pragma unroll
    for (int r = 0; r < 4; ++r) {
      const int row = rowB + mi * 16 + r;
      u16* crow = C + (size_t)row * 2048 + colB;
      float s = 0.f;
#pragma unroll
      for (int ni = 0; ni < 4; ++ni) {
        const u16 h = f2bf(__expf(acc[mi][ni][r]));
        crow[ni * 16] = h;
        s += bf2f(h);  // sum ROUNDED values -> exact convex combination
      }
#pragma unroll
      for (int m = 1; m <= 8; m <<= 1) s += __shfl_xor(s, m, 64);
      if (l15 == 0) prow[row] = s;
    }
}

// -------------------------------------------------- PV gemm + normalize
__global__ __launch_bounds__(256, 2) void gemm_pv(
    const u16* __restrict__ sbuf, const u16* __restrict__ vt,
    float* __restrict__ out, const float* __restrict__ part) {
  __shared__ u16 sA[128 * 128];
  __shared__ u16 sB[128 * 128];
  __shared__ float rowInv[128];
  const int tid = threadIdx.x;
  const int lane = tid & 63;
  const int wave = tid >> 6;
  const int quad = lane >> 4;
  const int l15 = lane & 15;
  const int wm = (wave >> 1) << 6;
  const int wn = (wave & 1) << 6;
  int tileM, tileN;
  swizzle_tiles(tileM, tileN);
  const int z = blockIdx.z;

  if (tid < 128) {
    const float* pp = part + (size_t)z * 32 * TT + tileM + tid;
    float s = 0.f;
#pragma unroll
    for (int j = 0; j < 32; ++j) s += pp[j * TT];
    rowInv[tid] = 1.0f / s;
  }
  // visible after the K-loop's barriers; consumed in epilogue

  const u16* A = sbuf + (size_t)z * TT * 2048 + (size_t)tileM * 2048;
  const u16* B = vt + (size_t)z * DD * TT + (size_t)tileN * 2048;

  f32x4 acc[4][4] = {};
  kloop_bt(A, B, 2048, 2048, sA, sB, acc);

  const int rowB = tileM + wm + quad * 4;
  const int colB = tileN + wn + l15;
  float* C = out + (size_t)z * TT * DD;
#pragma unroll
  for (int mi = 0; mi < 4; ++mi)
#pragma unroll
    for (int r = 0; r < 4; ++r) {
      const float inv = rowInv[wm + quad * 4 + mi * 16 + r];
      float* crow = C + (size_t)(rowB + mi * 16 + r) * DD + colB;
#pragma unroll
      for (int ni = 0; ni < 4; ++ni) crow[ni * 16] = acc[mi][ni][r] * inv;
    }
}

// ---------------------------------------------------------------- launcher
extern "C" void kernel_launch(void* const* d_in, const int* in_sizes, int n_in,
                              void* d_out, int out_size, void* d_ws,
                              size_t ws_size, hipStream_t stream) {
  const float* x = (const float*)d_in[0];
  const float* wq = (const float*)d_in[1];
  const float* bq = (const float*)d_in[2];
  const float* wk = (const float*)d_in[3];
  const float* bk = (const float*)d_in[4];
  const float* wv = (const float*)d_in[5];
  const float* bv = (const float*)d_in[6];
  float* out = (float*)d_out;

  const size_t MB = 1024 * 1024;
  // Workspace:
  //  [0,16)  xbf (dead after QKV); part [4][32][2048] fp32 aliases its head
  //          (written by gemm_s AFTER QKV consumed xbf).
  //  [16,22) wcat   [22,+12K) bcat
  //  [23,55) qk [8192][2048] bf16   [55,71) vt [4][1024][2048] bf16
  //  [71,103) sbuf [4][2048][2048] bf16 (unnormalized P)
  if (ws_size < 103 * MB) return;
  char* ws = (char*)d_ws;
  u16* xbf = (u16*)(ws);
  float* part = (float*)(ws);
  u16* wcat = (u16*)(ws + 16 * MB);
  float* bcat = (float*)(ws + 22 * MB);
  u16* qk = (u16*)(ws + 23 * MB);
  u16* vt = (u16*)(ws + 55 * MB);
  u16* sbuf = (u16*)(ws + 71 * MB);

  const dim3 blk(256);

  prep_kernel<<<5644, blk, 0, stream>>>(x, wq, wk, wv, bq, bk, bv, xbf, wcat,
                                        bcat);

  gemm_qkv<<<dim3(3 * DD / 128, BB * TT / 128, 1), blk, 0, stream>>>(
      xbf, wcat, qk, vt, bcat);

  gemm_s<<<dim3(TT / 128, TT / 128, BB), blk, 0, stream>>>(qk, sbuf, part);

  gemm_pv<<<dim3(DD / 128, TT / 128, BB), blk, 0, stream>>>(
      sbuf, vt, out, part);
}